// Round 13
// baseline (3266.694 us; speedup 1.0000x reference)
//
#include <hip/hip_runtime.h>

// ---------------------------------------------------------------------------
// VIN on MI355X (gfx950). B=128, H=W=64, C: 2 -> 150 -> 120 -> 100, q=10, K=36.
// R13: vs R12:
//   - conv2/conv3 LDS union: epilogue `outs` aliases Atile/Xs/w1s (dead by
//     then, barrier-separated) -> ~40KB LDS -> up to 4 blocks/CU (was 2).
//   - BN stats accumulated in registers inside the epilogue store loop
//     (shfl-xor quad reduce), replacing the 128-scalar-LDS-read stat pass.
//   - vi_step2: two VI iterations per launch (16-row tile, halo-4 staging,
//     intermediate v in LDS, exact zero-pad semantics); 36 -> 18 launches.
// NHWC bf16 t2 [524288][120], t3 [524288][104]; VI bufs aliased over dead t2.
// ---------------------------------------------------------------------------

#define NHW 524288.0f

typedef __attribute__((ext_vector_type(8))) short v8s;
typedef __attribute__((ext_vector_type(4))) float v4f;

static __device__ __forceinline__ float bf2f(unsigned short u) {
  return __uint_as_float(((unsigned int)u) << 16);
}
static __device__ __forceinline__ unsigned short f2bf(float f) {
  unsigned int x = __float_as_uint(f);
  return (unsigned short)((x + 0x7fffu + ((x >> 16) & 1u)) >> 16);  // RNE
}
static __device__ __forceinline__ float wave_sum(float s) {
  #pragma unroll
  for (int off = 32; off > 0; off >>= 1) s += __shfl_down(s, off, 64);
  return s;
}

// -------- weight repack: w[co][ci][3][3] f32 -> [9][128][CIP] bf16 ---------
template <int CO, int CI, int CIP>
__global__ __launch_bounds__(256) void repack_w(
    const float* __restrict__ w, unsigned short* __restrict__ Wp)
{
  int i = blockIdx.x * 256 + threadIdx.x;
  const int total = 9 * 128 * CIP;
  if (i >= total) return;
  int pos = i / (128 * CIP);
  int rem = i - pos * (128 * CIP);
  int co  = rem / CIP;
  int ci  = rem - co * CIP;
  float v = (co < CO && ci < CI) ? w[(co * CI + ci) * 9 + pos] : 0.f;
  Wp[i] = f2bf(v);
}

// ---------------- conv1 (2->150) stats-only, LDS-accumulated ---------------
__global__ __launch_bounds__(256) void conv1_stats(
    const float* __restrict__ X, const float* __restrict__ w1,
    const float* __restrict__ b1, float* __restrict__ S, float* __restrict__ Q)
{
  const int tile = blockIdx.x;             // 128*8
  const int b    = tile >> 3;
  const int y0t  = (tile & 7) * 8;
  const int co0  = blockIdx.y * 15;        // 10 groups of 15
  const int tid  = threadIdx.x;
  const int x    = tid & 63;
  const int ly0  = (tid >> 6) * 2;

  __shared__ float lin[2][10][66];
  __shared__ float ss[15], qq[15];
  if (tid < 15) { ss[tid] = 0.f; qq[tid] = 0.f; }
  for (int idx = tid; idx < 2 * 10 * 66; idx += 256) {
    int cc = idx / 660, rem = idx - cc * 660;
    int rr = rem / 66,  c   = rem - rr * 66;
    int yy = y0t + rr - 1, xx = c - 1;
    lin[cc][rr][c] = (yy >= 0 && yy < 64 && xx >= 0 && xx < 64)
                         ? X[((size_t)(b * 2 + cc) << 12) + (yy << 6) + xx] : 0.f;
  }
  __syncthreads();

  float iv[2][4][3];
  #pragma unroll
  for (int cc = 0; cc < 2; cc++)
    #pragma unroll
    for (int r = 0; r < 4; r++)
      #pragma unroll
      for (int c = 0; c < 3; c++) iv[cc][r][c] = lin[cc][ly0 + r][x + c];

  #pragma unroll
  for (int co = 0; co < 15; co++) {
    const float* w9 = w1 + (size_t)(co0 + co) * 18;
    float a0 = 0.f, a1 = 0.f;
    #pragma unroll
    for (int cc = 0; cc < 2; cc++)
      #pragma unroll
      for (int ky = 0; ky < 3; ky++)
        #pragma unroll
        for (int kx = 0; kx < 3; kx++) {
          float wv = w9[cc * 9 + ky * 3 + kx];
          a0 = fmaf(iv[cc][ky][kx],     wv, a0);
          a1 = fmaf(iv[cc][ky + 1][kx], wv, a1);
        }
    float bz = b1[co0 + co];
    float t0 = a0 + bz, t1 = a1 + bz;
    float s  = wave_sum(t0 + t1);
    float q  = wave_sum(t0 * t0 + t1 * t1);
    if ((tid & 63) == 0) { atomicAdd(&ss[co], s); atomicAdd(&qq[co], q); }
  }
  __syncthreads();
  if (tid < 15) {
    atomicAdd(&S[co0 + tid], ss[tid]);
    atomicAdd(&Q[co0 + tid], qq[tid]);
  }
}

// ---------------- BN finalize ----------------------------------------------
template <int C>
__global__ void bn_finalize(const float* __restrict__ S, const float* __restrict__ Q,
                            const float* __restrict__ g, const float* __restrict__ be,
                            float* __restrict__ A, float* __restrict__ Bs)
{
  int c = threadIdx.x;
  if (c < C) {
    const float invN = 1.f / NHW;
    float m   = S[c] * invN;
    float var = fmaxf(Q[c] * invN - m * m, 0.f);
    float sc  = g[c] * rsqrtf(var + 1e-5f);
    A[c]  = sc;
    Bs[c] = be[c] - m * sc;
  }
}

// ---------------- conv2 MFMA: 256px x 128co, LDS union, reg-stats ----------
__global__ __launch_bounds__(256, 3) void conv2_mfma(
    const float* __restrict__ X,  const float* __restrict__ w1,
    const float* __restrict__ b1f, const float* __restrict__ A1,
    const float* __restrict__ B1, const unsigned short* __restrict__ W2p,
    const float* __restrict__ b2, unsigned short* __restrict__ t2,
    float* __restrict__ S2, float* __restrict__ Q2)
{
  const int bx   = blockIdx.x;
  const int b    = bx >> 4;
  const int t16  = bx & 15;
  const int y0   = (t16 >> 2) * 16;
  const int x0   = (t16 & 3) * 16;
  const int tid  = threadIdx.x;
  const int lane = tid & 63;
  const int wid  = __builtin_amdgcn_readfirstlane(tid >> 6);
  const int ln   = lane & 15;
  const int quad = (lane >> 4) * 8;       // ushort offset within 32-ci chunk

  // LDS union: chunk phase = Xs(800f)|w1s(2700f)|A1s/B1s/b1s(450f)|Atile;
  //            epilogue    = outs[256*68] ushorts (aliases all of the above)
  __shared__ __align__(16) unsigned int U[9460];
  float*          Xs    = (float*)U;                 // [2*20*20]
  float*          w1s   = (float*)(U + 800);         // [2700]
  float*          A1s   = (float*)(U + 3500);        // [150]
  float*          B1s   = (float*)(U + 3650);        // [150]
  float*          b1s   = (float*)(U + 3800);        // [150]
  unsigned short* Atile = (unsigned short*)(U + 3952); // [324*34]
  unsigned short* outs  = (unsigned short*)U;        // [256*68]
  __shared__ float b2s[128], ssB[128], qqB[128];

  for (int i = tid; i < 2700; i += 256) w1s[i] = w1[i];
  for (int i = tid; i < 150; i += 256) { A1s[i] = A1[i]; B1s[i] = B1[i]; b1s[i] = b1f[i]; }
  if (tid < 128) { b2s[tid] = (tid < 120) ? b2[tid] : 0.f; ssB[tid] = 0.f; qqB[tid] = 0.f; }
  for (int i = tid; i < 800; i += 256) {
    int c2 = i / 400, rem = i - c2 * 400;
    int rr = rem / 20, cc = rem - rr * 20;
    int gy = y0 - 2 + rr, gx = x0 - 2 + cc;
    Xs[i] = (gy >= 0 && gy < 64 && gx >= 0 && gx < 64)
                ? X[((size_t)(b * 2 + c2) << 12) + (gy << 6) + gx] : 0.f;
  }

  v4f acc[4][8];
  #pragma unroll
  for (int i = 0; i < 4; i++)
    #pragma unroll
    for (int j = 0; j < 8; j++) acc[i][j] = (v4f){0.f, 0.f, 0.f, 0.f};

  for (int chunk = 0; chunk < 5; chunk++) {
    __syncthreads();                      // prior round's Atile reads done
    {
      // stage A chunk: h1 = relu(bn1(conv1(X))) for ci in [32c, 32c+32), fp32
      const int ci_loc = tid & 31;
      const int ci = chunk * 32 + ci_loc;
      const bool live = (ci < 150);
      float wv[18], sc = 0.f, sh = 0.f, bz = 0.f;
      if (live) {
        #pragma unroll
        for (int k = 0; k < 18; k++) wv[k] = w1s[ci * 18 + k];
        sc = A1s[ci]; sh = B1s[ci]; bz = b1s[ci];
      }
      for (int pass = 0; pass < 41; pass++) {
        int p = pass * 8 + (tid >> 5);
        if (p < 324) {
          float v = 0.f;
          if (live) {
            int pr = p / 18, pc = p - pr * 18;
            int hy = y0 - 1 + pr, hx = x0 - 1 + pc;
            if (hy >= 0 && hy < 64 && hx >= 0 && hx < 64) {
              float a = bz;
              #pragma unroll
              for (int c2 = 0; c2 < 2; c2++)
                #pragma unroll
                for (int ky = 0; ky < 3; ky++)
                  #pragma unroll
                  for (int kx = 0; kx < 3; kx++)
                    a = fmaf(Xs[c2 * 400 + (pr + ky) * 20 + (pc + kx)],
                             wv[c2 * 9 + ky * 3 + kx], a);
              v = fmaxf(fmaf(a, sc, sh), 0.f);
            }
          }
          Atile[p * 34 + ci_loc] = f2bf(v);
        }
      }
    }
    __syncthreads();

    // register-cache the 18 distinct A fragments for this round
    v8s afr[6][3];
    #pragma unroll
    for (int t = 0; t < 6; t++)
      #pragma unroll
      for (int kx = 0; kx < 3; kx++)
        afr[t][kx] = *(const v8s*)(&Atile[((wid * 4 + t) * 18 + ln + kx) * 34 + quad]);

    #pragma unroll
    for (int pos = 0; pos < 9; pos++) {
      const int ky = pos / 3, kx = pos - ky * 3;
      const unsigned short* bw =
          W2p + (size_t)(pos * 128 + ln) * 160 + chunk * 32 + quad;
      v8s bf[8];
      #pragma unroll
      for (int nj = 0; nj < 8; nj++)
        bf[nj] = *(const v8s*)(bw + (size_t)nj * 16 * 160);
      #pragma unroll
      for (int mi = 0; mi < 4; mi++) {
        #pragma unroll
        for (int nj = 0; nj < 8; nj++)
          acc[mi][nj] = __builtin_amdgcn_mfma_f32_16x16x32_bf16(
              afr[mi + ky][kx], bf[nj], acc[mi][nj], 0, 0, 0);
      }
    }
  }

  // epilogue: two 64-co halves through outs[256][68]; stores + reg-stats
  #pragma unroll
  for (int half = 0; half < 2; half++) {
    __syncthreads();                 // all afr reads done -> safe to alias
    #pragma unroll
    for (int njl = 0; njl < 4; njl++) {
      int n = njl * 16 + ln;
      float bz = b2s[half * 64 + n];
      float ls = 0.f, lq = 0.f;
      #pragma unroll
      for (int mi = 0; mi < 4; mi++)
        #pragma unroll
        for (int r2 = 0; r2 < 4; r2++) {
          int m = wid * 64 + mi * 16 + (lane >> 4) * 4 + r2;
          unsigned short us = f2bf(acc[mi][half * 4 + njl][r2] + bz);
          outs[m * 68 + n] = us;
          float v = bf2f(us);
          ls += v; lq += v * v;
        }
      ls += __shfl_xor(ls, 16); ls += __shfl_xor(ls, 32);
      lq += __shfl_xor(lq, 16); lq += __shfl_xor(lq, 32);
      if ((lane >> 4) == 0) {
        atomicAdd(&ssB[half * 64 + n], ls);
        atomicAdd(&qqB[half * 64 + n], lq);
      }
    }
    __syncthreads();
    const int ng = half ? 7 : 8;     // half1 -> co 64..119 (7 ushort8 groups)
    for (int i = tid; i < 256 * ng; i += 256) {
      int p = i / ng, g = i - p * ng;
      int gy = y0 + (p >> 4), gx = x0 + (p & 15);
      size_t gpx = ((size_t)b << 12) + (gy << 6) + gx;
      *(uint4*)(t2 + gpx * 120 + half * 64 + g * 8) =
          *(const uint4*)(&outs[p * 68 + g * 8]);
    }
  }
  __syncthreads();
  if (tid < 120) {
    atomicAdd(&S2[tid], ssB[tid]);
    atomicAdd(&Q2[tid], qqB[tid]);
  }
}

// ---------------- conv3 MFMA: 256px x 128co, LDS union, reg-stats ----------
__global__ __launch_bounds__(256, 3) void conv3_mfma(
    const unsigned short* __restrict__ t2, const float* __restrict__ A2,
    const float* __restrict__ B2, const unsigned short* __restrict__ W3p,
    const float* __restrict__ b3, unsigned short* __restrict__ t3,
    float* __restrict__ S3, float* __restrict__ Q3)
{
  const int bx   = blockIdx.x;
  const int b    = bx >> 4;
  const int t16  = bx & 15;
  const int y0   = (t16 >> 2) * 16;
  const int x0   = (t16 & 3) * 16;
  const int tid  = threadIdx.x;
  const int lane = tid & 63;
  const int wid  = __builtin_amdgcn_readfirstlane(tid >> 6);
  const int ln   = lane & 15;
  const int quad = (lane >> 4) * 8;

  // LDS union: chunk phase = Atile; epilogue = outs (aliases Atile)
  __shared__ __align__(16) unsigned int U[8704];
  unsigned short* Atile = (unsigned short*)U;   // [324*34]
  unsigned short* outs  = (unsigned short*)U;   // [256*68]
  __shared__ float A2s[120], B2s[120];
  __shared__ float b3s[128], ssB[128], qqB[128];

  for (int i = tid; i < 120; i += 256) { A2s[i] = A2[i]; B2s[i] = B2[i]; }
  if (tid < 128) { b3s[tid] = (tid < 100) ? b3[tid] : 0.f; ssB[tid] = 0.f; qqB[tid] = 0.f; }

  v4f acc[4][8];
  #pragma unroll
  for (int i = 0; i < 4; i++)
    #pragma unroll
    for (int j = 0; j < 8; j++) acc[i][j] = (v4f){0.f, 0.f, 0.f, 0.f};

  for (int chunk = 0; chunk < 4; chunk++) {
    __syncthreads();
    {
      // stage A chunk: BN2+ReLU(t2) halo, ci in [32c, 32c+32)
      const int ci0 = chunk * 32;
      const int ngr = (chunk == 3) ? 3 : 4;    // real uint4 groups (ci<120)
      for (int i = tid; i < 1296; i += 256) {  // 324 px x 4 groups
        int p = i >> 2, g = i & 3;
        int pr = p / 18, pc = p - pr * 18;
        int hy = y0 - 1 + pr, hx = x0 - 1 + pc;
        union { uint4 v; unsigned short u[8]; } ov;
        ov.v = (uint4){0, 0, 0, 0};
        if (g < ngr && hy >= 0 && hy < 64 && hx >= 0 && hx < 64) {
          size_t gpx = ((size_t)b << 12) + (hy << 6) + hx;
          union { uint4 v; unsigned short u[8]; } in;
          in.v = *(const uint4*)(t2 + gpx * 120 + ci0 + g * 8);
          #pragma unroll
          for (int j = 0; j < 8; j++) {
            int ci = ci0 + g * 8 + j;
            ov.u[j] = f2bf(fmaxf(fmaf(bf2f(in.u[j]), A2s[ci], B2s[ci]), 0.f));
          }
        }
        *(uint4*)(&Atile[p * 34 + g * 8]) = ov.v;
      }
    }
    __syncthreads();

    v8s afr[6][3];
    #pragma unroll
    for (int t = 0; t < 6; t++)
      #pragma unroll
      for (int kx = 0; kx < 3; kx++)
        afr[t][kx] = *(const v8s*)(&Atile[((wid * 4 + t) * 18 + ln + kx) * 34 + quad]);

    #pragma unroll
    for (int pos = 0; pos < 9; pos++) {
      const int ky = pos / 3, kx = pos - ky * 3;
      const unsigned short* bw =
          W3p + (size_t)(pos * 128 + ln) * 128 + chunk * 32 + quad;
      v8s bf[8];
      #pragma unroll
      for (int nj = 0; nj < 8; nj++)
        bf[nj] = *(const v8s*)(bw + (size_t)nj * 16 * 128);
      #pragma unroll
      for (int mi = 0; mi < 4; mi++) {
        #pragma unroll
        for (int nj = 0; nj < 8; nj++)
          acc[mi][nj] = __builtin_amdgcn_mfma_f32_16x16x32_bf16(
              afr[mi + ky][kx], bf[nj], acc[mi][nj], 0, 0, 0);
      }
    }
  }

  #pragma unroll
  for (int half = 0; half < 2; half++) {
    __syncthreads();
    #pragma unroll
    for (int njl = 0; njl < 4; njl++) {
      int n = njl * 16 + ln;
      float bz = b3s[half * 64 + n];   // 0 for co>=100 (weights also 0)
      float ls = 0.f, lq = 0.f;
      #pragma unroll
      for (int mi = 0; mi < 4; mi++)
        #pragma unroll
        for (int r2 = 0; r2 < 4; r2++) {
          int m = wid * 64 + mi * 16 + (lane >> 4) * 4 + r2;
          unsigned short us = f2bf(acc[mi][half * 4 + njl][r2] + bz);
          outs[m * 68 + n] = us;
          float v = bf2f(us);
          ls += v; lq += v * v;
        }
      ls += __shfl_xor(ls, 16); ls += __shfl_xor(ls, 32);
      lq += __shfl_xor(lq, 16); lq += __shfl_xor(lq, 32);
      if ((lane >> 4) == 0) {
        atomicAdd(&ssB[half * 64 + n], ls);
        atomicAdd(&qqB[half * 64 + n], lq);
      }
    }
    __syncthreads();
    const int ng = half ? 5 : 8;     // half1 -> co 64..103 (100..103 zeros)
    for (int i = tid; i < 256 * ng; i += 256) {
      int p = i / ng, g = i - p * ng;
      int gy = y0 + (p >> 4), gx = x0 + (p & 15);
      size_t gpx = ((size_t)b << 12) + (gy << 6) + gx;
      *(uint4*)(t3 + gpx * 104 + half * 64 + g * 8) =
          *(const uint4*)(&outs[p * 68 + g * 8]);
    }
  }
  __syncthreads();
  if (tid < 100) {
    atomicAdd(&S3[tid], ssB[tid]);
    atomicAdd(&Q3[tid], qqB[tid]);
  }
}

// ---------------- BN3+ReLU+1x1 reward reduce over NHWC t3 ------------------
__global__ __launch_bounds__(256) void bn3_reduce_r(
    const unsigned short* __restrict__ t3, const float* __restrict__ A3,
    const float* __restrict__ B3, const float* __restrict__ rw,
    float* __restrict__ r)
{
  __shared__ float A3s[104], B3s[104], rws[104];
  const int tid = threadIdx.x;
  for (int i = tid; i < 104; i += 256) {
    bool v = (i < 100);
    A3s[i] = v ? A3[i] : 0.f;
    B3s[i] = v ? B3[i] : 0.f;
    rws[i] = v ? rw[i] : 0.f;
  }
  __syncthreads();

  size_t px = (size_t)blockIdx.x * 256 + tid;
  const unsigned short* p = t3 + px * 104;
  float a = 0.f;
  #pragma unroll
  for (int gq = 0; gq < 13; gq++) {
    union { uint4 v; unsigned short u[8]; } in;
    in.v = *(const uint4*)(p + gq * 8);
    #pragma unroll
    for (int j = 0; j < 8; j++) {
      int ci = gq * 8 + j;
      a = fmaf(fmaxf(fmaf(bf2f(in.u[j]), A3s[ci], B3s[ci]), 0.f), rws[ci], a);
    }
  }
  r[px] = a;
}

// ---------------- qr = conv5x5(r, q_w) (bf16); v0 = max_a qr ---------------
__global__ __launch_bounds__(256) void qr_init(
    const float* __restrict__ r, const float* __restrict__ qw,
    unsigned short* __restrict__ qr, float* __restrict__ v0)
{
  const int tile = blockIdx.x;          // 128*16
  const int b    = tile >> 4;
  const int y0t  = (tile & 15) * 4;
  const int tid  = threadIdx.x;
  const int x    = tid & 63;
  const int ly   = tid >> 6;

  __shared__ float lv[8][68];
  for (int idx = tid; idx < 8 * 68; idx += 256) {
    int rr = idx / 68, c = idx - rr * 68;
    int yy = y0t + rr - 2, xx = c - 2;
    lv[rr][c] = (yy >= 0 && yy < 64 && xx >= 0 && xx < 64)
                    ? r[((size_t)b << 12) + (yy << 6) + xx] : 0.f;
  }
  __syncthreads();

  float iv[5][5];
  #pragma unroll
  for (int ky = 0; ky < 5; ky++)
    #pragma unroll
    for (int kx = 0; kx < 5; kx++) iv[ky][kx] = lv[ly + ky][x + kx];

  const int y = y0t + ly;
  float vmax = -1e30f;
  #pragma unroll
  for (int a = 0; a < 10; a++) {
    float q = 0.f;
    #pragma unroll
    for (int ky = 0; ky < 5; ky++)
      #pragma unroll
      for (int kx = 0; kx < 5; kx++)
        q = fmaf(iv[ky][kx], qw[a * 25 + ky * 5 + kx], q);
    qr[((size_t)(b * 10 + a) << 12) + (y << 6) + x] = f2bf(q);
    vmax = fmaxf(vmax, q);
  }
  v0[((size_t)b << 12) + (y << 6) + x] = vmax;
}

// ---------------- vi_step2: TWO VI iterations per launch -------------------
// 16-row output tile; stage vin halo-4 (24x72), intermediate (20x68) in LDS.
// Zero-padding semantics preserved exactly (invalid px stay 0).
__global__ __launch_bounds__(256) void vi_step2(
    const float* __restrict__ vin, const unsigned short* __restrict__ qr,
    const float* __restrict__ ww, float* __restrict__ vout)
{
  const int tile = blockIdx.x;      // 512 = 128 b x 4 tiles
  const int b    = tile >> 2;
  const int y0   = (tile & 3) * 16;
  const int tid  = threadIdx.x;

  __shared__ float lv[24][73];      // rows y0-4..y0+19, cols -4..67
  __shared__ float mid[20][69];     // rows y0-2..y0+17, cols -2..65
  __shared__ float wws[250];

  for (int i = tid; i < 250; i += 256) wws[i] = ww[i];

  for (int i = tid; i < 24 * 72; i += 256) {
    int rr = i / 72, cc = i - rr * 72;
    int yy = y0 - 4 + rr, xx = cc - 4;
    lv[rr][cc] = (yy >= 0 && yy < 64 && xx >= 0 && xx < 64)
                     ? vin[((size_t)b << 12) + (yy << 6) + xx] : 0.f;
  }
  __syncthreads();

  // step A: intermediate rows y0-2..y0+17 (valid px only; others 0)
  for (int i = tid; i < 20 * 68; i += 256) {
    int rr = i / 68, cc = i - rr * 68;
    int yy = y0 - 2 + rr, xx = cc - 2;
    float res = 0.f;
    if (yy >= 0 && yy < 64 && xx >= 0 && xx < 64) {
      float tap[25];
      #pragma unroll
      for (int t = 0; t < 25; t++) tap[t] = lv[rr + t / 5][cc + (t % 5)];
      float vmax = -1e30f;
      #pragma unroll
      for (int a = 0; a < 10; a++) {
        float q = bf2f(qr[((size_t)(b * 10 + a) << 12) + (yy << 6) + xx]);
        #pragma unroll
        for (int t = 0; t < 25; t++) q = fmaf(tap[t], wws[a * 25 + t], q);
        vmax = fmaxf(vmax, q);
      }
      res = vmax;
    }
    mid[rr][cc] = res;
  }
  __syncthreads();

  // step B: output rows y0..y0+15
  for (int i = tid; i < 16 * 64; i += 256) {
    int rr = i >> 6, xx = i & 63;
    int yy = y0 + rr;
    float tap[25];
    #pragma unroll
    for (int t = 0; t < 25; t++) tap[t] = mid[rr + t / 5][xx + (t % 5)];
    float vmax = -1e30f;
    #pragma unroll
    for (int a = 0; a < 10; a++) {
      float q = bf2f(qr[((size_t)(b * 10 + a) << 12) + (yy << 6) + xx]);
      #pragma unroll
      for (int t = 0; t < 25; t++) q = fmaf(tap[t], wws[a * 25 + t], q);
      vmax = fmaxf(vmax, q);
    }
    vout[((size_t)b << 12) + (yy << 6) + xx] = vmax;
  }
}

// ---------------- critic ---------------------------------------------------
__global__ __launch_bounds__(256) void critic_k(
    const float* __restrict__ v, const float* __restrict__ cvw,
    const float* __restrict__ cvb, float* __restrict__ out)
{
  const int b = blockIdx.x;
  const int tid = threadIdx.x;
  const float4* pv = (const float4*)(v + ((size_t)b << 12));
  const float4* pw = (const float4*)cvw;
  float s = 0.f;
  #pragma unroll
  for (int i = 0; i < 4; i++) {
    float4 a = pv[tid + 256 * i];
    float4 w = pw[tid + 256 * i];
    s += a.x * w.x + a.y * w.y + a.z * w.z + a.w * w.w;
  }
  s = wave_sum(s);
  __shared__ float ls[4];
  const int w = tid >> 6;
  if ((tid & 63) == 0) ls[w] = s;
  __syncthreads();
  if (tid == 0) out[b] = ls[0] + ls[1] + ls[2] + ls[3] + cvb[0];
}

// ---------------- action MLP ----------------------------------------------
__global__ __launch_bounds__(128) void action_k(
    const float* __restrict__ obs, const float* __restrict__ fc1w,
    const float* __restrict__ fc1b, const float* __restrict__ fc2w,
    const float* __restrict__ fc2b, float* __restrict__ out)
{
  const int b = blockIdx.x;
  const int j = threadIdx.x;
  __shared__ float ob[24];
  __shared__ float h[100];
  if (j < 24) ob[j] = obs[b * 24 + j];
  __syncthreads();
  if (j < 100) {
    float s = fc1b[j];
    #pragma unroll
    for (int k = 0; k < 24; k++) s = fmaf(ob[k], fc1w[j * 24 + k], s);
    h[j] = fmaxf(s, 0.f);
  }
  __syncthreads();
  if (j < 10) {
    float s = fc2b[j];
    for (int k = 0; k < 100; k++) s = fmaf(h[k], fc2w[j * 100 + k], s);
    out[128 + b * 10 + j] = fmaxf(s, 0.f);
  }
}

// ---------------------------------------------------------------------------
extern "C" void kernel_launch(void* const* d_in, const int* in_sizes, int n_in,
                              void* d_out, int out_size, void* d_ws,
                              size_t ws_size, hipStream_t stream)
{
  const float* X     = (const float*)d_in[0];
  const float* obs   = (const float*)d_in[1];
  const float* h1_w  = (const float*)d_in[2];
  const float* h1_b  = (const float*)d_in[3];
  const float* g1    = (const float*)d_in[4];
  const float* b1    = (const float*)d_in[5];
  const float* h2_w  = (const float*)d_in[6];
  const float* h2_b  = (const float*)d_in[7];
  const float* g2    = (const float*)d_in[8];
  const float* b2    = (const float*)d_in[9];
  const float* h3_w  = (const float*)d_in[10];
  const float* h3_b  = (const float*)d_in[11];
  const float* g3    = (const float*)d_in[12];
  const float* b3    = (const float*)d_in[13];
  const float* r_w   = (const float*)d_in[14];
  const float* q_w   = (const float*)d_in[15];
  const float* w_vi  = (const float*)d_in[16];
  const float* fc1_w = (const float*)d_in[17];
  const float* fc1_b = (const float*)d_in[18];
  const float* fc2_w = (const float*)d_in[19];
  const float* fc2_b = (const float*)d_in[20];
  const float* cv_w  = (const float*)d_in[21];
  const float* cv_b  = (const float*)d_in[22];
  // K (d_in[23]) fixed to 36 by setup; loop count is compile-time.

  char* ws = (char*)d_ws;
  unsigned short* t2  = (unsigned short*)ws;                       // 125,829,120 B
  unsigned short* t3  = (unsigned short*)(ws + 125829120ull);      // 109,051,904 B
  unsigned short* W2p = (unsigned short*)(ws + 234881024ull);      //     368,640 B
  unsigned short* W3p = (unsigned short*)(ws + 235249664ull);      //     294,912 B
  float*          ST  = (float*)         (ws + 235544576ull);      //       5,920 B
  float* S1 = ST +    0; float* Q1 = ST +  150; float* A1 = ST +  300; float* B1 = ST +  450;
  float* S2 = ST +  600; float* Q2 = ST +  720; float* A2 = ST +  840; float* B2 = ST +  960;
  float* S3 = ST + 1080; float* Q3 = ST + 1180; float* A3 = ST + 1280; float* B3 = ST + 1380;
  // VI buffers aliased over dead t2 region:
  float*          r   = (float*)ws;                          // 2,097,152 B
  unsigned short* qrh = (unsigned short*)(ws + 2097152ull);  // 10,485,760 B (bf16)
  float*          vA  = (float*)(ws + 12582912ull);          // 2,097,152 B
  float*          vB  = (float*)(ws + 14680064ull);          // 2,097,152 B

  hipMemsetAsync(ST, 0, 1480 * sizeof(float), stream);

  repack_w<120, 150, 160><<<720, 256, 0, stream>>>(h2_w, W2p);
  repack_w<100, 120, 128><<<576, 256, 0, stream>>>(h3_w, W3p);

  conv1_stats<<<dim3(1024, 10), 256, 0, stream>>>(X, h1_w, h1_b, S1, Q1);
  bn_finalize<150><<<1, 256, 0, stream>>>(S1, Q1, g1, b1, A1, B1);

  conv2_mfma<<<2048, 256, 0, stream>>>(X, h1_w, h1_b, A1, B1, W2p, h2_b, t2, S2, Q2);
  bn_finalize<120><<<1, 256, 0, stream>>>(S2, Q2, g2, b2, A2, B2);

  conv3_mfma<<<2048, 256, 0, stream>>>(t2, A2, B2, W3p, h3_b, t3, S3, Q3);
  bn_finalize<100><<<1, 256, 0, stream>>>(S3, Q3, g3, b3, A3, B3);

  bn3_reduce_r<<<2048, 256, 0, stream>>>(t3, A3, B3, r_w, r);

  qr_init<<<2048, 256, 0, stream>>>(r, q_w, qrh, vA);
  // 36 steps = 18 double-steps; final result lands in vA
  for (int i = 0; i < 18; i++) {
    const float* vin = (i & 1) ? vB : vA;
    float* vout      = (i & 1) ? vA : vB;
    vi_step2<<<512, 256, 0, stream>>>(vin, qrh, w_vi, vout);
  }

  float* out = (float*)d_out;
  critic_k<<<128, 256, 0, stream>>>(vA, cv_w, cv_b, out);
  action_k<<<128, 128, 0, stream>>>(obs, fc1_w, fc1_b, fc2_w, fc2_b, out);
}

// Round 14
// 1573.555 us; speedup vs baseline: 2.0760x; 2.0760x over previous
//
#include <hip/hip_runtime.h>

// ---------------------------------------------------------------------------
// VIN on MI355X (gfx950). B=128, H=W=64, C: 2 -> 150 -> 120 -> 100, q=10, K=36.
// R14 = R13 with the launch-bounds fix: __launch_bounds__(256,2) (R13's
// (256,3) made the allocator target 6 waves/SIMD -> 84 VGPR -> the 128-float
// acc tile spilled to scratch -> 6.4 GB HBM traffic/launch). LDS union keeps
// ~39KB -> occupancy now LDS-limited at 4 blocks/CU with no spill.
// NHWC bf16 t2 [524288][120], t3 [524288][104]; VI bufs aliased over dead t2.
// ---------------------------------------------------------------------------

#define NHW 524288.0f

typedef __attribute__((ext_vector_type(8))) short v8s;
typedef __attribute__((ext_vector_type(4))) float v4f;

static __device__ __forceinline__ float bf2f(unsigned short u) {
  return __uint_as_float(((unsigned int)u) << 16);
}
static __device__ __forceinline__ unsigned short f2bf(float f) {
  unsigned int x = __float_as_uint(f);
  return (unsigned short)((x + 0x7fffu + ((x >> 16) & 1u)) >> 16);  // RNE
}
static __device__ __forceinline__ float wave_sum(float s) {
  #pragma unroll
  for (int off = 32; off > 0; off >>= 1) s += __shfl_down(s, off, 64);
  return s;
}

// -------- weight repack: w[co][ci][3][3] f32 -> [9][128][CIP] bf16 ---------
template <int CO, int CI, int CIP>
__global__ __launch_bounds__(256) void repack_w(
    const float* __restrict__ w, unsigned short* __restrict__ Wp)
{
  int i = blockIdx.x * 256 + threadIdx.x;
  const int total = 9 * 128 * CIP;
  if (i >= total) return;
  int pos = i / (128 * CIP);
  int rem = i - pos * (128 * CIP);
  int co  = rem / CIP;
  int ci  = rem - co * CIP;
  float v = (co < CO && ci < CI) ? w[(co * CI + ci) * 9 + pos] : 0.f;
  Wp[i] = f2bf(v);
}

// ---------------- conv1 (2->150) stats-only, LDS-accumulated ---------------
__global__ __launch_bounds__(256) void conv1_stats(
    const float* __restrict__ X, const float* __restrict__ w1,
    const float* __restrict__ b1, float* __restrict__ S, float* __restrict__ Q)
{
  const int tile = blockIdx.x;             // 128*8
  const int b    = tile >> 3;
  const int y0t  = (tile & 7) * 8;
  const int co0  = blockIdx.y * 15;        // 10 groups of 15
  const int tid  = threadIdx.x;
  const int x    = tid & 63;
  const int ly0  = (tid >> 6) * 2;

  __shared__ float lin[2][10][66];
  __shared__ float ss[15], qq[15];
  if (tid < 15) { ss[tid] = 0.f; qq[tid] = 0.f; }
  for (int idx = tid; idx < 2 * 10 * 66; idx += 256) {
    int cc = idx / 660, rem = idx - cc * 660;
    int rr = rem / 66,  c   = rem - rr * 66;
    int yy = y0t + rr - 1, xx = c - 1;
    lin[cc][rr][c] = (yy >= 0 && yy < 64 && xx >= 0 && xx < 64)
                         ? X[((size_t)(b * 2 + cc) << 12) + (yy << 6) + xx] : 0.f;
  }
  __syncthreads();

  float iv[2][4][3];
  #pragma unroll
  for (int cc = 0; cc < 2; cc++)
    #pragma unroll
    for (int r = 0; r < 4; r++)
      #pragma unroll
      for (int c = 0; c < 3; c++) iv[cc][r][c] = lin[cc][ly0 + r][x + c];

  #pragma unroll
  for (int co = 0; co < 15; co++) {
    const float* w9 = w1 + (size_t)(co0 + co) * 18;
    float a0 = 0.f, a1 = 0.f;
    #pragma unroll
    for (int cc = 0; cc < 2; cc++)
      #pragma unroll
      for (int ky = 0; ky < 3; ky++)
        #pragma unroll
        for (int kx = 0; kx < 3; kx++) {
          float wv = w9[cc * 9 + ky * 3 + kx];
          a0 = fmaf(iv[cc][ky][kx],     wv, a0);
          a1 = fmaf(iv[cc][ky + 1][kx], wv, a1);
        }
    float bz = b1[co0 + co];
    float t0 = a0 + bz, t1 = a1 + bz;
    float s  = wave_sum(t0 + t1);
    float q  = wave_sum(t0 * t0 + t1 * t1);
    if ((tid & 63) == 0) { atomicAdd(&ss[co], s); atomicAdd(&qq[co], q); }
  }
  __syncthreads();
  if (tid < 15) {
    atomicAdd(&S[co0 + tid], ss[tid]);
    atomicAdd(&Q[co0 + tid], qq[tid]);
  }
}

// ---------------- BN finalize ----------------------------------------------
template <int C>
__global__ void bn_finalize(const float* __restrict__ S, const float* __restrict__ Q,
                            const float* __restrict__ g, const float* __restrict__ be,
                            float* __restrict__ A, float* __restrict__ Bs)
{
  int c = threadIdx.x;
  if (c < C) {
    const float invN = 1.f / NHW;
    float m   = S[c] * invN;
    float var = fmaxf(Q[c] * invN - m * m, 0.f);
    float sc  = g[c] * rsqrtf(var + 1e-5f);
    A[c]  = sc;
    Bs[c] = be[c] - m * sc;
  }
}

// ---------------- conv2 MFMA: 256px x 128co, LDS union, reg-stats ----------
__global__ __launch_bounds__(256, 2) void conv2_mfma(
    const float* __restrict__ X,  const float* __restrict__ w1,
    const float* __restrict__ b1f, const float* __restrict__ A1,
    const float* __restrict__ B1, const unsigned short* __restrict__ W2p,
    const float* __restrict__ b2, unsigned short* __restrict__ t2,
    float* __restrict__ S2, float* __restrict__ Q2)
{
  const int bx   = blockIdx.x;
  const int b    = bx >> 4;
  const int t16  = bx & 15;
  const int y0   = (t16 >> 2) * 16;
  const int x0   = (t16 & 3) * 16;
  const int tid  = threadIdx.x;
  const int lane = tid & 63;
  const int wid  = __builtin_amdgcn_readfirstlane(tid >> 6);
  const int ln   = lane & 15;
  const int quad = (lane >> 4) * 8;       // ushort offset within 32-ci chunk

  // LDS union: chunk phase = Xs(800f)|w1s(2700f)|A1s/B1s/b1s(450f)|Atile;
  //            epilogue    = outs[256*68] ushorts (aliases all of the above)
  __shared__ __align__(16) unsigned int U[9460];
  float*          Xs    = (float*)U;                 // [2*20*20]
  float*          w1s   = (float*)(U + 800);         // [2700]
  float*          A1s   = (float*)(U + 3500);        // [150]
  float*          B1s   = (float*)(U + 3650);        // [150]
  float*          b1s   = (float*)(U + 3800);        // [150]
  unsigned short* Atile = (unsigned short*)(U + 3952); // [324*34]
  unsigned short* outs  = (unsigned short*)U;        // [256*68]
  __shared__ float b2s[128], ssB[128], qqB[128];

  for (int i = tid; i < 2700; i += 256) w1s[i] = w1[i];
  for (int i = tid; i < 150; i += 256) { A1s[i] = A1[i]; B1s[i] = B1[i]; b1s[i] = b1f[i]; }
  if (tid < 128) { b2s[tid] = (tid < 120) ? b2[tid] : 0.f; ssB[tid] = 0.f; qqB[tid] = 0.f; }
  for (int i = tid; i < 800; i += 256) {
    int c2 = i / 400, rem = i - c2 * 400;
    int rr = rem / 20, cc = rem - rr * 20;
    int gy = y0 - 2 + rr, gx = x0 - 2 + cc;
    Xs[i] = (gy >= 0 && gy < 64 && gx >= 0 && gx < 64)
                ? X[((size_t)(b * 2 + c2) << 12) + (gy << 6) + gx] : 0.f;
  }

  v4f acc[4][8];
  #pragma unroll
  for (int i = 0; i < 4; i++)
    #pragma unroll
    for (int j = 0; j < 8; j++) acc[i][j] = (v4f){0.f, 0.f, 0.f, 0.f};

  for (int chunk = 0; chunk < 5; chunk++) {
    __syncthreads();                      // prior round's Atile reads done
    {
      // stage A chunk: h1 = relu(bn1(conv1(X))) for ci in [32c, 32c+32), fp32
      const int ci_loc = tid & 31;
      const int ci = chunk * 32 + ci_loc;
      const bool live = (ci < 150);
      float wv[18], sc = 0.f, sh = 0.f, bz = 0.f;
      if (live) {
        #pragma unroll
        for (int k = 0; k < 18; k++) wv[k] = w1s[ci * 18 + k];
        sc = A1s[ci]; sh = B1s[ci]; bz = b1s[ci];
      }
      for (int pass = 0; pass < 41; pass++) {
        int p = pass * 8 + (tid >> 5);
        if (p < 324) {
          float v = 0.f;
          if (live) {
            int pr = p / 18, pc = p - pr * 18;
            int hy = y0 - 1 + pr, hx = x0 - 1 + pc;
            if (hy >= 0 && hy < 64 && hx >= 0 && hx < 64) {
              float a = bz;
              #pragma unroll
              for (int c2 = 0; c2 < 2; c2++)
                #pragma unroll
                for (int ky = 0; ky < 3; ky++)
                  #pragma unroll
                  for (int kx = 0; kx < 3; kx++)
                    a = fmaf(Xs[c2 * 400 + (pr + ky) * 20 + (pc + kx)],
                             wv[c2 * 9 + ky * 3 + kx], a);
              v = fmaxf(fmaf(a, sc, sh), 0.f);
            }
          }
          Atile[p * 34 + ci_loc] = f2bf(v);
        }
      }
    }
    __syncthreads();

    // register-cache the 18 distinct A fragments for this round
    v8s afr[6][3];
    #pragma unroll
    for (int t = 0; t < 6; t++)
      #pragma unroll
      for (int kx = 0; kx < 3; kx++)
        afr[t][kx] = *(const v8s*)(&Atile[((wid * 4 + t) * 18 + ln + kx) * 34 + quad]);

    #pragma unroll
    for (int pos = 0; pos < 9; pos++) {
      const int ky = pos / 3, kx = pos - ky * 3;
      const unsigned short* bw =
          W2p + (size_t)(pos * 128 + ln) * 160 + chunk * 32 + quad;
      v8s bf[8];
      #pragma unroll
      for (int nj = 0; nj < 8; nj++)
        bf[nj] = *(const v8s*)(bw + (size_t)nj * 16 * 160);
      #pragma unroll
      for (int mi = 0; mi < 4; mi++) {
        #pragma unroll
        for (int nj = 0; nj < 8; nj++)
          acc[mi][nj] = __builtin_amdgcn_mfma_f32_16x16x32_bf16(
              afr[mi + ky][kx], bf[nj], acc[mi][nj], 0, 0, 0);
      }
    }
  }

  // epilogue: two 64-co halves through outs[256][68]; stores + reg-stats
  #pragma unroll
  for (int half = 0; half < 2; half++) {
    __syncthreads();                 // all afr reads done -> safe to alias
    #pragma unroll
    for (int njl = 0; njl < 4; njl++) {
      int n = njl * 16 + ln;
      float bz = b2s[half * 64 + n];
      float ls = 0.f, lq = 0.f;
      #pragma unroll
      for (int mi = 0; mi < 4; mi++)
        #pragma unroll
        for (int r2 = 0; r2 < 4; r2++) {
          int m = wid * 64 + mi * 16 + (lane >> 4) * 4 + r2;
          unsigned short us = f2bf(acc[mi][half * 4 + njl][r2] + bz);
          outs[m * 68 + n] = us;
          float v = bf2f(us);
          ls += v; lq += v * v;
        }
      ls += __shfl_xor(ls, 16); ls += __shfl_xor(ls, 32);
      lq += __shfl_xor(lq, 16); lq += __shfl_xor(lq, 32);
      if ((lane >> 4) == 0) {
        atomicAdd(&ssB[half * 64 + n], ls);
        atomicAdd(&qqB[half * 64 + n], lq);
      }
    }
    __syncthreads();
    const int ng = half ? 7 : 8;     // half1 -> co 64..119 (7 ushort8 groups)
    for (int i = tid; i < 256 * ng; i += 256) {
      int p = i / ng, g = i - p * ng;
      int gy = y0 + (p >> 4), gx = x0 + (p & 15);
      size_t gpx = ((size_t)b << 12) + (gy << 6) + gx;
      *(uint4*)(t2 + gpx * 120 + half * 64 + g * 8) =
          *(const uint4*)(&outs[p * 68 + g * 8]);
    }
  }
  __syncthreads();
  if (tid < 120) {
    atomicAdd(&S2[tid], ssB[tid]);
    atomicAdd(&Q2[tid], qqB[tid]);
  }
}

// ---------------- conv3 MFMA: 256px x 128co, LDS union, reg-stats ----------
__global__ __launch_bounds__(256, 2) void conv3_mfma(
    const unsigned short* __restrict__ t2, const float* __restrict__ A2,
    const float* __restrict__ B2, const unsigned short* __restrict__ W3p,
    const float* __restrict__ b3, unsigned short* __restrict__ t3,
    float* __restrict__ S3, float* __restrict__ Q3)
{
  const int bx   = blockIdx.x;
  const int b    = bx >> 4;
  const int t16  = bx & 15;
  const int y0   = (t16 >> 2) * 16;
  const int x0   = (t16 & 3) * 16;
  const int tid  = threadIdx.x;
  const int lane = tid & 63;
  const int wid  = __builtin_amdgcn_readfirstlane(tid >> 6);
  const int ln   = lane & 15;
  const int quad = (lane >> 4) * 8;

  // LDS union: chunk phase = Atile; epilogue = outs (aliases Atile)
  __shared__ __align__(16) unsigned int U[8704];
  unsigned short* Atile = (unsigned short*)U;   // [324*34]
  unsigned short* outs  = (unsigned short*)U;   // [256*68]
  __shared__ float A2s[120], B2s[120];
  __shared__ float b3s[128], ssB[128], qqB[128];

  for (int i = tid; i < 120; i += 256) { A2s[i] = A2[i]; B2s[i] = B2[i]; }
  if (tid < 128) { b3s[tid] = (tid < 100) ? b3[tid] : 0.f; ssB[tid] = 0.f; qqB[tid] = 0.f; }

  v4f acc[4][8];
  #pragma unroll
  for (int i = 0; i < 4; i++)
    #pragma unroll
    for (int j = 0; j < 8; j++) acc[i][j] = (v4f){0.f, 0.f, 0.f, 0.f};

  for (int chunk = 0; chunk < 4; chunk++) {
    __syncthreads();
    {
      // stage A chunk: BN2+ReLU(t2) halo, ci in [32c, 32c+32)
      const int ci0 = chunk * 32;
      const int ngr = (chunk == 3) ? 3 : 4;    // real uint4 groups (ci<120)
      for (int i = tid; i < 1296; i += 256) {  // 324 px x 4 groups
        int p = i >> 2, g = i & 3;
        int pr = p / 18, pc = p - pr * 18;
        int hy = y0 - 1 + pr, hx = x0 - 1 + pc;
        union { uint4 v; unsigned short u[8]; } ov;
        ov.v = (uint4){0, 0, 0, 0};
        if (g < ngr && hy >= 0 && hy < 64 && hx >= 0 && hx < 64) {
          size_t gpx = ((size_t)b << 12) + (hy << 6) + hx;
          union { uint4 v; unsigned short u[8]; } in;
          in.v = *(const uint4*)(t2 + gpx * 120 + ci0 + g * 8);
          #pragma unroll
          for (int j = 0; j < 8; j++) {
            int ci = ci0 + g * 8 + j;
            ov.u[j] = f2bf(fmaxf(fmaf(bf2f(in.u[j]), A2s[ci], B2s[ci]), 0.f));
          }
        }
        *(uint4*)(&Atile[p * 34 + g * 8]) = ov.v;
      }
    }
    __syncthreads();

    v8s afr[6][3];
    #pragma unroll
    for (int t = 0; t < 6; t++)
      #pragma unroll
      for (int kx = 0; kx < 3; kx++)
        afr[t][kx] = *(const v8s*)(&Atile[((wid * 4 + t) * 18 + ln + kx) * 34 + quad]);

    #pragma unroll
    for (int pos = 0; pos < 9; pos++) {
      const int ky = pos / 3, kx = pos - ky * 3;
      const unsigned short* bw =
          W3p + (size_t)(pos * 128 + ln) * 128 + chunk * 32 + quad;
      v8s bf[8];
      #pragma unroll
      for (int nj = 0; nj < 8; nj++)
        bf[nj] = *(const v8s*)(bw + (size_t)nj * 16 * 128);
      #pragma unroll
      for (int mi = 0; mi < 4; mi++) {
        #pragma unroll
        for (int nj = 0; nj < 8; nj++)
          acc[mi][nj] = __builtin_amdgcn_mfma_f32_16x16x32_bf16(
              afr[mi + ky][kx], bf[nj], acc[mi][nj], 0, 0, 0);
      }
    }
  }

  #pragma unroll
  for (int half = 0; half < 2; half++) {
    __syncthreads();
    #pragma unroll
    for (int njl = 0; njl < 4; njl++) {
      int n = njl * 16 + ln;
      float bz = b3s[half * 64 + n];   // 0 for co>=100 (weights also 0)
      float ls = 0.f, lq = 0.f;
      #pragma unroll
      for (int mi = 0; mi < 4; mi++)
        #pragma unroll
        for (int r2 = 0; r2 < 4; r2++) {
          int m = wid * 64 + mi * 16 + (lane >> 4) * 4 + r2;
          unsigned short us = f2bf(acc[mi][half * 4 + njl][r2] + bz);
          outs[m * 68 + n] = us;
          float v = bf2f(us);
          ls += v; lq += v * v;
        }
      ls += __shfl_xor(ls, 16); ls += __shfl_xor(ls, 32);
      lq += __shfl_xor(lq, 16); lq += __shfl_xor(lq, 32);
      if ((lane >> 4) == 0) {
        atomicAdd(&ssB[half * 64 + n], ls);
        atomicAdd(&qqB[half * 64 + n], lq);
      }
    }
    __syncthreads();
    const int ng = half ? 5 : 8;     // half1 -> co 64..103 (100..103 zeros)
    for (int i = tid; i < 256 * ng; i += 256) {
      int p = i / ng, g = i - p * ng;
      int gy = y0 + (p >> 4), gx = x0 + (p & 15);
      size_t gpx = ((size_t)b << 12) + (gy << 6) + gx;
      *(uint4*)(t3 + gpx * 104 + half * 64 + g * 8) =
          *(const uint4*)(&outs[p * 68 + g * 8]);
    }
  }
  __syncthreads();
  if (tid < 100) {
    atomicAdd(&S3[tid], ssB[tid]);
    atomicAdd(&Q3[tid], qqB[tid]);
  }
}

// ---------------- BN3+ReLU+1x1 reward reduce over NHWC t3 ------------------
__global__ __launch_bounds__(256) void bn3_reduce_r(
    const unsigned short* __restrict__ t3, const float* __restrict__ A3,
    const float* __restrict__ B3, const float* __restrict__ rw,
    float* __restrict__ r)
{
  __shared__ float A3s[104], B3s[104], rws[104];
  const int tid = threadIdx.x;
  for (int i = tid; i < 104; i += 256) {
    bool v = (i < 100);
    A3s[i] = v ? A3[i] : 0.f;
    B3s[i] = v ? B3[i] : 0.f;
    rws[i] = v ? rw[i] : 0.f;
  }
  __syncthreads();

  size_t px = (size_t)blockIdx.x * 256 + tid;
  const unsigned short* p = t3 + px * 104;
  float a = 0.f;
  #pragma unroll
  for (int gq = 0; gq < 13; gq++) {
    union { uint4 v; unsigned short u[8]; } in;
    in.v = *(const uint4*)(p + gq * 8);
    #pragma unroll
    for (int j = 0; j < 8; j++) {
      int ci = gq * 8 + j;
      a = fmaf(fmaxf(fmaf(bf2f(in.u[j]), A3s[ci], B3s[ci]), 0.f), rws[ci], a);
    }
  }
  r[px] = a;
}

// ---------------- qr = conv5x5(r, q_w) (bf16); v0 = max_a qr ---------------
__global__ __launch_bounds__(256) void qr_init(
    const float* __restrict__ r, const float* __restrict__ qw,
    unsigned short* __restrict__ qr, float* __restrict__ v0)
{
  const int tile = blockIdx.x;          // 128*16
  const int b    = tile >> 4;
  const int y0t  = (tile & 15) * 4;
  const int tid  = threadIdx.x;
  const int x    = tid & 63;
  const int ly   = tid >> 6;

  __shared__ float lv[8][68];
  for (int idx = tid; idx < 8 * 68; idx += 256) {
    int rr = idx / 68, c = idx - rr * 68;
    int yy = y0t + rr - 2, xx = c - 2;
    lv[rr][c] = (yy >= 0 && yy < 64 && xx >= 0 && xx < 64)
                    ? r[((size_t)b << 12) + (yy << 6) + xx] : 0.f;
  }
  __syncthreads();

  float iv[5][5];
  #pragma unroll
  for (int ky = 0; ky < 5; ky++)
    #pragma unroll
    for (int kx = 0; kx < 5; kx++) iv[ky][kx] = lv[ly + ky][x + kx];

  const int y = y0t + ly;
  float vmax = -1e30f;
  #pragma unroll
  for (int a = 0; a < 10; a++) {
    float q = 0.f;
    #pragma unroll
    for (int ky = 0; ky < 5; ky++)
      #pragma unroll
      for (int kx = 0; kx < 5; kx++)
        q = fmaf(iv[ky][kx], qw[a * 25 + ky * 5 + kx], q);
    qr[((size_t)(b * 10 + a) << 12) + (y << 6) + x] = f2bf(q);
    vmax = fmaxf(vmax, q);
  }
  v0[((size_t)b << 12) + (y << 6) + x] = vmax;
}

// ---------------- vi_step2: TWO VI iterations per launch -------------------
__global__ __launch_bounds__(256) void vi_step2(
    const float* __restrict__ vin, const unsigned short* __restrict__ qr,
    const float* __restrict__ ww, float* __restrict__ vout)
{
  const int tile = blockIdx.x;      // 512 = 128 b x 4 tiles
  const int b    = tile >> 2;
  const int y0   = (tile & 3) * 16;
  const int tid  = threadIdx.x;

  __shared__ float lv[24][73];      // rows y0-4..y0+19, cols -4..67
  __shared__ float mid[20][69];     // rows y0-2..y0+17, cols -2..65
  __shared__ float wws[250];

  for (int i = tid; i < 250; i += 256) wws[i] = ww[i];

  for (int i = tid; i < 24 * 72; i += 256) {
    int rr = i / 72, cc = i - rr * 72;
    int yy = y0 - 4 + rr, xx = cc - 4;
    lv[rr][cc] = (yy >= 0 && yy < 64 && xx >= 0 && xx < 64)
                     ? vin[((size_t)b << 12) + (yy << 6) + xx] : 0.f;
  }
  __syncthreads();

  // step A: intermediate rows y0-2..y0+17 (valid px only; others 0)
  for (int i = tid; i < 20 * 68; i += 256) {
    int rr = i / 68, cc = i - rr * 68;
    int yy = y0 - 2 + rr, xx = cc - 2;
    float res = 0.f;
    if (yy >= 0 && yy < 64 && xx >= 0 && xx < 64) {
      float tap[25];
      #pragma unroll
      for (int t = 0; t < 25; t++) tap[t] = lv[rr + t / 5][cc + (t % 5)];
      float vmax = -1e30f;
      #pragma unroll
      for (int a = 0; a < 10; a++) {
        float q = bf2f(qr[((size_t)(b * 10 + a) << 12) + (yy << 6) + xx]);
        #pragma unroll
        for (int t = 0; t < 25; t++) q = fmaf(tap[t], wws[a * 25 + t], q);
        vmax = fmaxf(vmax, q);
      }
      res = vmax;
    }
    mid[rr][cc] = res;
  }
  __syncthreads();

  // step B: output rows y0..y0+15
  for (int i = tid; i < 16 * 64; i += 256) {
    int rr = i >> 6, xx = i & 63;
    int yy = y0 + rr;
    float tap[25];
    #pragma unroll
    for (int t = 0; t < 25; t++) tap[t] = mid[rr + t / 5][xx + (t % 5)];
    float vmax = -1e30f;
    #pragma unroll
    for (int a = 0; a < 10; a++) {
      float q = bf2f(qr[((size_t)(b * 10 + a) << 12) + (yy << 6) + xx]);
      #pragma unroll
      for (int t = 0; t < 25; t++) q = fmaf(tap[t], wws[a * 25 + t], q);
      vmax = fmaxf(vmax, q);
    }
    vout[((size_t)b << 12) + (yy << 6) + xx] = vmax;
  }
}

// ---------------- critic ---------------------------------------------------
__global__ __launch_bounds__(256) void critic_k(
    const float* __restrict__ v, const float* __restrict__ cvw,
    const float* __restrict__ cvb, float* __restrict__ out)
{
  const int b = blockIdx.x;
  const int tid = threadIdx.x;
  const float4* pv = (const float4*)(v + ((size_t)b << 12));
  const float4* pw = (const float4*)cvw;
  float s = 0.f;
  #pragma unroll
  for (int i = 0; i < 4; i++) {
    float4 a = pv[tid + 256 * i];
    float4 w = pw[tid + 256 * i];
    s += a.x * w.x + a.y * w.y + a.z * w.z + a.w * w.w;
  }
  s = wave_sum(s);
  __shared__ float ls[4];
  const int w = tid >> 6;
  if ((tid & 63) == 0) ls[w] = s;
  __syncthreads();
  if (tid == 0) out[b] = ls[0] + ls[1] + ls[2] + ls[3] + cvb[0];
}

// ---------------- action MLP ----------------------------------------------
__global__ __launch_bounds__(128) void action_k(
    const float* __restrict__ obs, const float* __restrict__ fc1w,
    const float* __restrict__ fc1b, const float* __restrict__ fc2w,
    const float* __restrict__ fc2b, float* __restrict__ out)
{
  const int b = blockIdx.x;
  const int j = threadIdx.x;
  __shared__ float ob[24];
  __shared__ float h[100];
  if (j < 24) ob[j] = obs[b * 24 + j];
  __syncthreads();
  if (j < 100) {
    float s = fc1b[j];
    #pragma unroll
    for (int k = 0; k < 24; k++) s = fmaf(ob[k], fc1w[j * 24 + k], s);
    h[j] = fmaxf(s, 0.f);
  }
  __syncthreads();
  if (j < 10) {
    float s = fc2b[j];
    for (int k = 0; k < 100; k++) s = fmaf(h[k], fc2w[j * 100 + k], s);
    out[128 + b * 10 + j] = fmaxf(s, 0.f);
  }
}

// ---------------------------------------------------------------------------
extern "C" void kernel_launch(void* const* d_in, const int* in_sizes, int n_in,
                              void* d_out, int out_size, void* d_ws,
                              size_t ws_size, hipStream_t stream)
{
  const float* X     = (const float*)d_in[0];
  const float* obs   = (const float*)d_in[1];
  const float* h1_w  = (const float*)d_in[2];
  const float* h1_b  = (const float*)d_in[3];
  const float* g1    = (const float*)d_in[4];
  const float* b1    = (const float*)d_in[5];
  const float* h2_w  = (const float*)d_in[6];
  const float* h2_b  = (const float*)d_in[7];
  const float* g2    = (const float*)d_in[8];
  const float* b2    = (const float*)d_in[9];
  const float* h3_w  = (const float*)d_in[10];
  const float* h3_b  = (const float*)d_in[11];
  const float* g3    = (const float*)d_in[12];
  const float* b3    = (const float*)d_in[13];
  const float* r_w   = (const float*)d_in[14];
  const float* q_w   = (const float*)d_in[15];
  const float* w_vi  = (const float*)d_in[16];
  const float* fc1_w = (const float*)d_in[17];
  const float* fc1_b = (const float*)d_in[18];
  const float* fc2_w = (const float*)d_in[19];
  const float* fc2_b = (const float*)d_in[20];
  const float* cv_w  = (const float*)d_in[21];
  const float* cv_b  = (const float*)d_in[22];
  // K (d_in[23]) fixed to 36 by setup; loop count is compile-time.

  char* ws = (char*)d_ws;
  unsigned short* t2  = (unsigned short*)ws;                       // 125,829,120 B
  unsigned short* t3  = (unsigned short*)(ws + 125829120ull);      // 109,051,904 B
  unsigned short* W2p = (unsigned short*)(ws + 234881024ull);      //     368,640 B
  unsigned short* W3p = (unsigned short*)(ws + 235249664ull);      //     294,912 B
  float*          ST  = (float*)         (ws + 235544576ull);      //       5,920 B
  float* S1 = ST +    0; float* Q1 = ST +  150; float* A1 = ST +  300; float* B1 = ST +  450;
  float* S2 = ST +  600; float* Q2 = ST +  720; float* A2 = ST +  840; float* B2 = ST +  960;
  float* S3 = ST + 1080; float* Q3 = ST + 1180; float* A3 = ST + 1280; float* B3 = ST + 1380;
  // VI buffers aliased over dead t2 region:
  float*          r   = (float*)ws;                          // 2,097,152 B
  unsigned short* qrh = (unsigned short*)(ws + 2097152ull);  // 10,485,760 B (bf16)
  float*          vA  = (float*)(ws + 12582912ull);          // 2,097,152 B
  float*          vB  = (float*)(ws + 14680064ull);          // 2,097,152 B

  hipMemsetAsync(ST, 0, 1480 * sizeof(float), stream);

  repack_w<120, 150, 160><<<720, 256, 0, stream>>>(h2_w, W2p);
  repack_w<100, 120, 128><<<576, 256, 0, stream>>>(h3_w, W3p);

  conv1_stats<<<dim3(1024, 10), 256, 0, stream>>>(X, h1_w, h1_b, S1, Q1);
  bn_finalize<150><<<1, 256, 0, stream>>>(S1, Q1, g1, b1, A1, B1);

  conv2_mfma<<<2048, 256, 0, stream>>>(X, h1_w, h1_b, A1, B1, W2p, h2_b, t2, S2, Q2);
  bn_finalize<120><<<1, 256, 0, stream>>>(S2, Q2, g2, b2, A2, B2);

  conv3_mfma<<<2048, 256, 0, stream>>>(t2, A2, B2, W3p, h3_b, t3, S3, Q3);
  bn_finalize<100><<<1, 256, 0, stream>>>(S3, Q3, g3, b3, A3, B3);

  bn3_reduce_r<<<2048, 256, 0, stream>>>(t3, A3, B3, r_w, r);

  qr_init<<<2048, 256, 0, stream>>>(r, q_w, qrh, vA);
  // 36 steps = 18 double-steps; final result lands in vA
  for (int i = 0; i < 18; i++) {
    const float* vin = (i & 1) ? vB : vA;
    float* vout      = (i & 1) ? vA : vB;
    vi_step2<<<512, 256, 0, stream>>>(vin, qrh, w_vi, vout);
  }

  float* out = (float*)d_out;
  critic_k<<<128, 256, 0, stream>>>(vA, cv_w, cv_b, out);
  action_k<<<128, 128, 0, stream>>>(obs, fc1_w, fc1_b, fc2_w, fc2_b, out);
}

// Round 16
// 1295.119 us; speedup vs baseline: 2.5223x; 1.2150x over previous
//
#include <hip/hip_runtime.h>

// ---------------------------------------------------------------------------
// VIN on MI355X (gfx950). B=128, H=W=64, C: 2 -> 150 -> 120 -> 100, q=10, K=36.
// R16 = R12 verbatim (best measured: 1292 us, absmax 0.0078). R15's
// persistent-VI spin barrier deadlocked (co-residency not guaranteed);
// R11/R14 VI restructurings also regressed -> separate full-grid VI kernels
// are the proven optimum for this harness.
//   - conv2/conv3: MFMA implicit GEMM, 256px x 128co/block, B-frags direct
//     from L2-resident repacked weights, BN stats fused into epilogues.
//   - qr stored bf16 (halves VI-phase qr traffic).
// NHWC bf16 t2 [524288][120], t3 [524288][104]; VI bufs aliased over dead t2.
// ---------------------------------------------------------------------------

#define NHW 524288.0f

typedef __attribute__((ext_vector_type(8))) short v8s;
typedef __attribute__((ext_vector_type(4))) float v4f;

static __device__ __forceinline__ float bf2f(unsigned short u) {
  return __uint_as_float(((unsigned int)u) << 16);
}
static __device__ __forceinline__ unsigned short f2bf(float f) {
  unsigned int x = __float_as_uint(f);
  return (unsigned short)((x + 0x7fffu + ((x >> 16) & 1u)) >> 16);  // RNE
}
static __device__ __forceinline__ float wave_sum(float s) {
  #pragma unroll
  for (int off = 32; off > 0; off >>= 1) s += __shfl_down(s, off, 64);
  return s;
}

// -------- weight repack: w[co][ci][3][3] f32 -> [9][128][CIP] bf16 ---------
template <int CO, int CI, int CIP>
__global__ __launch_bounds__(256) void repack_w(
    const float* __restrict__ w, unsigned short* __restrict__ Wp)
{
  int i = blockIdx.x * 256 + threadIdx.x;
  const int total = 9 * 128 * CIP;
  if (i >= total) return;
  int pos = i / (128 * CIP);
  int rem = i - pos * (128 * CIP);
  int co  = rem / CIP;
  int ci  = rem - co * CIP;
  float v = (co < CO && ci < CI) ? w[(co * CI + ci) * 9 + pos] : 0.f;
  Wp[i] = f2bf(v);
}

// ---------------- conv1 (2->150) stats-only, LDS-accumulated ---------------
__global__ __launch_bounds__(256) void conv1_stats(
    const float* __restrict__ X, const float* __restrict__ w1,
    const float* __restrict__ b1, float* __restrict__ S, float* __restrict__ Q)
{
  const int tile = blockIdx.x;             // 128*8
  const int b    = tile >> 3;
  const int y0t  = (tile & 7) * 8;
  const int co0  = blockIdx.y * 15;        // 10 groups of 15
  const int tid  = threadIdx.x;
  const int x    = tid & 63;
  const int ly0  = (tid >> 6) * 2;

  __shared__ float lin[2][10][66];
  __shared__ float ss[15], qq[15];
  if (tid < 15) { ss[tid] = 0.f; qq[tid] = 0.f; }
  for (int idx = tid; idx < 2 * 10 * 66; idx += 256) {
    int cc = idx / 660, rem = idx - cc * 660;
    int rr = rem / 66,  c   = rem - rr * 66;
    int yy = y0t + rr - 1, xx = c - 1;
    lin[cc][rr][c] = (yy >= 0 && yy < 64 && xx >= 0 && xx < 64)
                         ? X[((size_t)(b * 2 + cc) << 12) + (yy << 6) + xx] : 0.f;
  }
  __syncthreads();

  float iv[2][4][3];
  #pragma unroll
  for (int cc = 0; cc < 2; cc++)
    #pragma unroll
    for (int r = 0; r < 4; r++)
      #pragma unroll
      for (int c = 0; c < 3; c++) iv[cc][r][c] = lin[cc][ly0 + r][x + c];

  #pragma unroll
  for (int co = 0; co < 15; co++) {
    const float* w9 = w1 + (size_t)(co0 + co) * 18;
    float a0 = 0.f, a1 = 0.f;
    #pragma unroll
    for (int cc = 0; cc < 2; cc++)
      #pragma unroll
      for (int ky = 0; ky < 3; ky++)
        #pragma unroll
        for (int kx = 0; kx < 3; kx++) {
          float wv = w9[cc * 9 + ky * 3 + kx];
          a0 = fmaf(iv[cc][ky][kx],     wv, a0);
          a1 = fmaf(iv[cc][ky + 1][kx], wv, a1);
        }
    float bz = b1[co0 + co];
    float t0 = a0 + bz, t1 = a1 + bz;
    float s  = wave_sum(t0 + t1);
    float q  = wave_sum(t0 * t0 + t1 * t1);
    if ((tid & 63) == 0) { atomicAdd(&ss[co], s); atomicAdd(&qq[co], q); }
  }
  __syncthreads();
  if (tid < 15) {
    atomicAdd(&S[co0 + tid], ss[tid]);
    atomicAdd(&Q[co0 + tid], qq[tid]);
  }
}

// ---------------- BN finalize ----------------------------------------------
template <int C>
__global__ void bn_finalize(const float* __restrict__ S, const float* __restrict__ Q,
                            const float* __restrict__ g, const float* __restrict__ be,
                            float* __restrict__ A, float* __restrict__ Bs)
{
  int c = threadIdx.x;
  if (c < C) {
    const float invN = 1.f / NHW;
    float m   = S[c] * invN;
    float var = fmaxf(Q[c] * invN - m * m, 0.f);
    float sc  = g[c] * rsqrtf(var + 1e-5f);
    A[c]  = sc;
    Bs[c] = be[c] - m * sc;
  }
}

// ---------------- conv2 MFMA: 256px x 128co, B from global, stats fused ----
__global__ __launch_bounds__(256, 2) void conv2_mfma(
    const float* __restrict__ X,  const float* __restrict__ w1,
    const float* __restrict__ b1f, const float* __restrict__ A1,
    const float* __restrict__ B1, const unsigned short* __restrict__ W2p,
    const float* __restrict__ b2, unsigned short* __restrict__ t2,
    float* __restrict__ S2, float* __restrict__ Q2)
{
  const int bx   = blockIdx.x;
  const int b    = bx >> 4;
  const int t16  = bx & 15;
  const int y0   = (t16 >> 2) * 16;
  const int x0   = (t16 & 3) * 16;
  const int tid  = threadIdx.x;
  const int lane = tid & 63;
  const int wid  = __builtin_amdgcn_readfirstlane(tid >> 6);
  const int ln   = lane & 15;
  const int quad = (lane >> 4) * 8;       // ushort offset within 32-ci chunk

  __shared__ __align__(16) float Xs[2][20][20];
  __shared__ float w1s[2700];
  __shared__ float A1s[150], B1s[150], b1s[150], b2s[128];
  __shared__ float ssB[128], qqB[128];
  __shared__ __align__(16) unsigned short Atile[324 * 34];   // halo px x ci-chunk
  __shared__ __align__(16) unsigned short outs[256 * 68];    // epilogue buffer

  for (int i = tid; i < 2700; i += 256) w1s[i] = w1[i];
  for (int i = tid; i < 150; i += 256) { A1s[i] = A1[i]; B1s[i] = B1[i]; b1s[i] = b1f[i]; }
  if (tid < 128) { b2s[tid] = (tid < 120) ? b2[tid] : 0.f; ssB[tid] = 0.f; qqB[tid] = 0.f; }
  for (int i = tid; i < 800; i += 256) {
    int c2 = i / 400, rem = i - c2 * 400;
    int rr = rem / 20, cc = rem - rr * 20;
    int gy = y0 - 2 + rr, gx = x0 - 2 + cc;
    Xs[c2][rr][cc] = (gy >= 0 && gy < 64 && gx >= 0 && gx < 64)
                         ? X[((size_t)(b * 2 + c2) << 12) + (gy << 6) + gx] : 0.f;
  }

  v4f acc[4][8];
  #pragma unroll
  for (int i = 0; i < 4; i++)
    #pragma unroll
    for (int j = 0; j < 8; j++) acc[i][j] = (v4f){0.f, 0.f, 0.f, 0.f};

  for (int chunk = 0; chunk < 5; chunk++) {
    __syncthreads();                      // prior round's Atile reads done
    {
      // stage A chunk: h1 = relu(bn1(conv1(X))) for ci in [32c, 32c+32), fp32
      const int ci_loc = tid & 31;
      const int ci = chunk * 32 + ci_loc;
      const bool live = (ci < 150);
      float wv[18], sc = 0.f, sh = 0.f, bz = 0.f;
      if (live) {
        #pragma unroll
        for (int k = 0; k < 18; k++) wv[k] = w1s[ci * 18 + k];
        sc = A1s[ci]; sh = B1s[ci]; bz = b1s[ci];
      }
      for (int pass = 0; pass < 41; pass++) {
        int p = pass * 8 + (tid >> 5);
        if (p < 324) {
          float v = 0.f;
          if (live) {
            int pr = p / 18, pc = p - pr * 18;
            int hy = y0 - 1 + pr, hx = x0 - 1 + pc;
            if (hy >= 0 && hy < 64 && hx >= 0 && hx < 64) {
              float a = bz;
              #pragma unroll
              for (int c2 = 0; c2 < 2; c2++)
                #pragma unroll
                for (int ky = 0; ky < 3; ky++)
                  #pragma unroll
                  for (int kx = 0; kx < 3; kx++)
                    a = fmaf(Xs[c2][pr + ky][pc + kx], wv[c2 * 9 + ky * 3 + kx], a);
              v = fmaxf(fmaf(a, sc, sh), 0.f);
            }
          }
          Atile[p * 34 + ci_loc] = f2bf(v);
        }
      }
    }
    __syncthreads();

    // register-cache the 18 distinct A fragments for this round
    v8s afr[6][3];
    #pragma unroll
    for (int t = 0; t < 6; t++)
      #pragma unroll
      for (int kx = 0; kx < 3; kx++)
        afr[t][kx] = *(const v8s*)(&Atile[((wid * 4 + t) * 18 + ln + kx) * 34 + quad]);

    #pragma unroll
    for (int pos = 0; pos < 9; pos++) {
      const int ky = pos / 3, kx = pos - ky * 3;
      const unsigned short* bw =
          W2p + (size_t)(pos * 128 + ln) * 160 + chunk * 32 + quad;
      v8s bf[8];
      #pragma unroll
      for (int nj = 0; nj < 8; nj++)
        bf[nj] = *(const v8s*)(bw + (size_t)nj * 16 * 160);
      #pragma unroll
      for (int mi = 0; mi < 4; mi++) {
        #pragma unroll
        for (int nj = 0; nj < 8; nj++)
          acc[mi][nj] = __builtin_amdgcn_mfma_f32_16x16x32_bf16(
              afr[mi + ky][kx], bf[nj], acc[mi][nj], 0, 0, 0);
      }
    }
  }

  // epilogue: two 64-co halves through outs[256][68]; stores + stats
  #pragma unroll
  for (int half = 0; half < 2; half++) {
    __syncthreads();
    #pragma unroll
    for (int mi = 0; mi < 4; mi++)
      #pragma unroll
      for (int njl = 0; njl < 4; njl++) {
        int n = njl * 16 + ln;
        float bz = b2s[half * 64 + n];
        #pragma unroll
        for (int r2 = 0; r2 < 4; r2++) {
          int m = wid * 64 + mi * 16 + (lane >> 4) * 4 + r2;
          outs[m * 68 + n] = f2bf(acc[mi][half * 4 + njl][r2] + bz);
        }
      }
    __syncthreads();
    const int ng = half ? 7 : 8;     // half1 -> co 64..119 (7 ushort8 groups)
    for (int i = tid; i < 256 * ng; i += 256) {
      int p = i / ng, g = i - p * ng;
      int gy = y0 + (p >> 4), gx = x0 + (p & 15);
      size_t gpx = ((size_t)b << 12) + (gy << 6) + gx;
      *(uint4*)(t2 + gpx * 120 + half * 64 + g * 8) =
          *(const uint4*)(&outs[p * 68 + g * 8]);
    }
    // fused BN2 stats from the stored (bf16) values
    {
      float ls = 0.f, lq = 0.f;
      const int c = tid & 63, pr0 = (tid >> 6) * 64;
      for (int p = 0; p < 64; p++) {
        float v = bf2f(outs[(pr0 + p) * 68 + c]);
        ls += v; lq += v * v;
      }
      atomicAdd(&ssB[half * 64 + c], ls);
      atomicAdd(&qqB[half * 64 + c], lq);
    }
  }
  __syncthreads();
  if (tid < 120) {
    atomicAdd(&S2[tid], ssB[tid]);
    atomicAdd(&Q2[tid], qqB[tid]);
  }
}

// ---------------- conv3 MFMA: 256px x 128co, B from global, stats fused ----
__global__ __launch_bounds__(256, 2) void conv3_mfma(
    const unsigned short* __restrict__ t2, const float* __restrict__ A2,
    const float* __restrict__ B2, const unsigned short* __restrict__ W3p,
    const float* __restrict__ b3, unsigned short* __restrict__ t3,
    float* __restrict__ S3, float* __restrict__ Q3)
{
  const int bx   = blockIdx.x;
  const int b    = bx >> 4;
  const int t16  = bx & 15;
  const int y0   = (t16 >> 2) * 16;
  const int x0   = (t16 & 3) * 16;
  const int tid  = threadIdx.x;
  const int lane = tid & 63;
  const int wid  = __builtin_amdgcn_readfirstlane(tid >> 6);
  const int ln   = lane & 15;
  const int quad = (lane >> 4) * 8;

  __shared__ float A2s[120], B2s[120], b3s[128];
  __shared__ float ssB[128], qqB[128];
  __shared__ __align__(16) unsigned short Atile[324 * 34];
  __shared__ __align__(16) unsigned short outs[256 * 68];

  for (int i = tid; i < 120; i += 256) { A2s[i] = A2[i]; B2s[i] = B2[i]; }
  if (tid < 128) { b3s[tid] = (tid < 100) ? b3[tid] : 0.f; ssB[tid] = 0.f; qqB[tid] = 0.f; }

  v4f acc[4][8];
  #pragma unroll
  for (int i = 0; i < 4; i++)
    #pragma unroll
    for (int j = 0; j < 8; j++) acc[i][j] = (v4f){0.f, 0.f, 0.f, 0.f};

  for (int chunk = 0; chunk < 4; chunk++) {
    __syncthreads();
    {
      // stage A chunk: BN2+ReLU(t2) halo, ci in [32c, 32c+32)
      const int ci0 = chunk * 32;
      const int ngr = (chunk == 3) ? 3 : 4;    // real uint4 groups (ci<120)
      for (int i = tid; i < 1296; i += 256) {  // 324 px x 4 groups
        int p = i >> 2, g = i & 3;
        int pr = p / 18, pc = p - pr * 18;
        int hy = y0 - 1 + pr, hx = x0 - 1 + pc;
        union { uint4 v; unsigned short u[8]; } ov;
        ov.v = (uint4){0, 0, 0, 0};
        if (g < ngr && hy >= 0 && hy < 64 && hx >= 0 && hx < 64) {
          size_t gpx = ((size_t)b << 12) + (hy << 6) + hx;
          union { uint4 v; unsigned short u[8]; } in;
          in.v = *(const uint4*)(t2 + gpx * 120 + ci0 + g * 8);
          #pragma unroll
          for (int j = 0; j < 8; j++) {
            int ci = ci0 + g * 8 + j;
            ov.u[j] = f2bf(fmaxf(fmaf(bf2f(in.u[j]), A2s[ci], B2s[ci]), 0.f));
          }
        }
        *(uint4*)(&Atile[p * 34 + g * 8]) = ov.v;
      }
    }
    __syncthreads();

    v8s afr[6][3];
    #pragma unroll
    for (int t = 0; t < 6; t++)
      #pragma unroll
      for (int kx = 0; kx < 3; kx++)
        afr[t][kx] = *(const v8s*)(&Atile[((wid * 4 + t) * 18 + ln + kx) * 34 + quad]);

    #pragma unroll
    for (int pos = 0; pos < 9; pos++) {
      const int ky = pos / 3, kx = pos - ky * 3;
      const unsigned short* bw =
          W3p + (size_t)(pos * 128 + ln) * 128 + chunk * 32 + quad;
      v8s bf[8];
      #pragma unroll
      for (int nj = 0; nj < 8; nj++)
        bf[nj] = *(const v8s*)(bw + (size_t)nj * 16 * 128);
      #pragma unroll
      for (int mi = 0; mi < 4; mi++) {
        #pragma unroll
        for (int nj = 0; nj < 8; nj++)
          acc[mi][nj] = __builtin_amdgcn_mfma_f32_16x16x32_bf16(
              afr[mi + ky][kx], bf[nj], acc[mi][nj], 0, 0, 0);
      }
    }
  }

  #pragma unroll
  for (int half = 0; half < 2; half++) {
    __syncthreads();
    #pragma unroll
    for (int mi = 0; mi < 4; mi++)
      #pragma unroll
      for (int njl = 0; njl < 4; njl++) {
        int n = njl * 16 + ln;
        float bz = b3s[half * 64 + n];   // 0 for co>=100 (weights also 0)
        #pragma unroll
        for (int r2 = 0; r2 < 4; r2++) {
          int m = wid * 64 + mi * 16 + (lane >> 4) * 4 + r2;
          outs[m * 68 + n] = f2bf(acc[mi][half * 4 + njl][r2] + bz);
        }
      }
    __syncthreads();
    const int ng = half ? 5 : 8;     // half1 -> co 64..103 (100..103 zeros)
    for (int i = tid; i < 256 * ng; i += 256) {
      int p = i / ng, g = i - p * ng;
      int gy = y0 + (p >> 4), gx = x0 + (p & 15);
      size_t gpx = ((size_t)b << 12) + (gy << 6) + gx;
      *(uint4*)(t3 + gpx * 104 + half * 64 + g * 8) =
          *(const uint4*)(&outs[p * 68 + g * 8]);
    }
    {
      float ls = 0.f, lq = 0.f;
      const int c = tid & 63, pr0 = (tid >> 6) * 64;
      for (int p = 0; p < 64; p++) {
        float v = bf2f(outs[(pr0 + p) * 68 + c]);
        ls += v; lq += v * v;
      }
      atomicAdd(&ssB[half * 64 + c], ls);
      atomicAdd(&qqB[half * 64 + c], lq);
    }
  }
  __syncthreads();
  if (tid < 100) {
    atomicAdd(&S3[tid], ssB[tid]);
    atomicAdd(&Q3[tid], qqB[tid]);
  }
}

// ---------------- BN3+ReLU+1x1 reward reduce over NHWC t3 ------------------
__global__ __launch_bounds__(256) void bn3_reduce_r(
    const unsigned short* __restrict__ t3, const float* __restrict__ A3,
    const float* __restrict__ B3, const float* __restrict__ rw,
    float* __restrict__ r)
{
  __shared__ float A3s[104], B3s[104], rws[104];
  const int tid = threadIdx.x;
  for (int i = tid; i < 104; i += 256) {
    bool v = (i < 100);
    A3s[i] = v ? A3[i] : 0.f;
    B3s[i] = v ? B3[i] : 0.f;
    rws[i] = v ? rw[i] : 0.f;
  }
  __syncthreads();

  size_t px = (size_t)blockIdx.x * 256 + tid;
  const unsigned short* p = t3 + px * 104;
  float a = 0.f;
  #pragma unroll
  for (int gq = 0; gq < 13; gq++) {
    union { uint4 v; unsigned short u[8]; } in;
    in.v = *(const uint4*)(p + gq * 8);
    #pragma unroll
    for (int j = 0; j < 8; j++) {
      int ci = gq * 8 + j;
      a = fmaf(fmaxf(fmaf(bf2f(in.u[j]), A3s[ci], B3s[ci]), 0.f), rws[ci], a);
    }
  }
  r[px] = a;
}

// ---------------- qr = conv5x5(r, q_w) (bf16); v0 = max_a qr ---------------
__global__ __launch_bounds__(256) void qr_init(
    const float* __restrict__ r, const float* __restrict__ qw,
    unsigned short* __restrict__ qr, float* __restrict__ v0)
{
  const int tile = blockIdx.x;          // 128*16
  const int b    = tile >> 4;
  const int y0t  = (tile & 15) * 4;
  const int tid  = threadIdx.x;
  const int x    = tid & 63;
  const int ly   = tid >> 6;

  __shared__ float lv[8][68];
  for (int idx = tid; idx < 8 * 68; idx += 256) {
    int rr = idx / 68, c = idx - rr * 68;
    int yy = y0t + rr - 2, xx = c - 2;
    lv[rr][c] = (yy >= 0 && yy < 64 && xx >= 0 && xx < 64)
                    ? r[((size_t)b << 12) + (yy << 6) + xx] : 0.f;
  }
  __syncthreads();

  float iv[5][5];
  #pragma unroll
  for (int ky = 0; ky < 5; ky++)
    #pragma unroll
    for (int kx = 0; kx < 5; kx++) iv[ky][kx] = lv[ly + ky][x + kx];

  const int y = y0t + ly;
  float vmax = -1e30f;
  #pragma unroll
  for (int a = 0; a < 10; a++) {
    float q = 0.f;
    #pragma unroll
    for (int ky = 0; ky < 5; ky++)
      #pragma unroll
      for (int kx = 0; kx < 5; kx++)
        q = fmaf(iv[ky][kx], qw[a * 25 + ky * 5 + kx], q);
    qr[((size_t)(b * 10 + a) << 12) + (y << 6) + x] = f2bf(q);
    vmax = fmaxf(vmax, q);
  }
  v0[((size_t)b << 12) + (y << 6) + x] = vmax;
}

// ---------------- VI step: v' = max_a (qr + conv5x5(v, w)) -----------------
__global__ __launch_bounds__(256) void vi_step(
    const float* __restrict__ vin, const unsigned short* __restrict__ qr,
    const float* __restrict__ ww, float* __restrict__ vout)
{
  const int tile = blockIdx.x;
  const int b    = tile >> 4;
  const int y0t  = (tile & 15) * 4;
  const int tid  = threadIdx.x;
  const int x    = tid & 63;
  const int ly   = tid >> 6;

  __shared__ float lv[8][68];
  for (int idx = tid; idx < 8 * 68; idx += 256) {
    int rr = idx / 68, c = idx - rr * 68;
    int yy = y0t + rr - 2, xx = c - 2;
    lv[rr][c] = (yy >= 0 && yy < 64 && xx >= 0 && xx < 64)
                    ? vin[((size_t)b << 12) + (yy << 6) + xx] : 0.f;
  }
  __syncthreads();

  float iv[5][5];
  #pragma unroll
  for (int ky = 0; ky < 5; ky++)
    #pragma unroll
    for (int kx = 0; kx < 5; kx++) iv[ky][kx] = lv[ly + ky][x + kx];

  const int y = y0t + ly;
  float vmax = -1e30f;
  #pragma unroll
  for (int a = 0; a < 10; a++) {
    float q = bf2f(qr[((size_t)(b * 10 + a) << 12) + (y << 6) + x]);
    #pragma unroll
    for (int ky = 0; ky < 5; ky++)
      #pragma unroll
      for (int kx = 0; kx < 5; kx++)
        q = fmaf(iv[ky][kx], ww[a * 25 + ky * 5 + kx], q);
    vmax = fmaxf(vmax, q);
  }
  vout[((size_t)b << 12) + (y << 6) + x] = vmax;
}

// ---------------- critic ---------------------------------------------------
__global__ __launch_bounds__(256) void critic_k(
    const float* __restrict__ v, const float* __restrict__ cvw,
    const float* __restrict__ cvb, float* __restrict__ out)
{
  const int b = blockIdx.x;
  const int tid = threadIdx.x;
  const float4* pv = (const float4*)(v + ((size_t)b << 12));
  const float4* pw = (const float4*)cvw;
  float s = 0.f;
  #pragma unroll
  for (int i = 0; i < 4; i++) {
    float4 a = pv[tid + 256 * i];
    float4 w = pw[tid + 256 * i];
    s += a.x * w.x + a.y * w.y + a.z * w.z + a.w * w.w;
  }
  s = wave_sum(s);
  __shared__ float ls[4];
  const int w = tid >> 6;
  if ((tid & 63) == 0) ls[w] = s;
  __syncthreads();
  if (tid == 0) out[b] = ls[0] + ls[1] + ls[2] + ls[3] + cvb[0];
}

// ---------------- action MLP ----------------------------------------------
__global__ __launch_bounds__(128) void action_k(
    const float* __restrict__ obs, const float* __restrict__ fc1w,
    const float* __restrict__ fc1b, const float* __restrict__ fc2w,
    const float* __restrict__ fc2b, float* __restrict__ out)
{
  const int b = blockIdx.x;
  const int j = threadIdx.x;
  __shared__ float ob[24];
  __shared__ float h[100];
  if (j < 24) ob[j] = obs[b * 24 + j];
  __syncthreads();
  if (j < 100) {
    float s = fc1b[j];
    #pragma unroll
    for (int k = 0; k < 24; k++) s = fmaf(ob[k], fc1w[j * 24 + k], s);
    h[j] = fmaxf(s, 0.f);
  }
  __syncthreads();
  if (j < 10) {
    float s = fc2b[j];
    for (int k = 0; k < 100; k++) s = fmaf(h[k], fc2w[j * 100 + k], s);
    out[128 + b * 10 + j] = fmaxf(s, 0.f);
  }
}

// ---------------------------------------------------------------------------
extern "C" void kernel_launch(void* const* d_in, const int* in_sizes, int n_in,
                              void* d_out, int out_size, void* d_ws,
                              size_t ws_size, hipStream_t stream)
{
  const float* X     = (const float*)d_in[0];
  const float* obs   = (const float*)d_in[1];
  const float* h1_w  = (const float*)d_in[2];
  const float* h1_b  = (const float*)d_in[3];
  const float* g1    = (const float*)d_in[4];
  const float* b1    = (const float*)d_in[5];
  const float* h2_w  = (const float*)d_in[6];
  const float* h2_b  = (const float*)d_in[7];
  const float* g2    = (const float*)d_in[8];
  const float* b2    = (const float*)d_in[9];
  const float* h3_w  = (const float*)d_in[10];
  const float* h3_b  = (const float*)d_in[11];
  const float* g3    = (const float*)d_in[12];
  const float* b3    = (const float*)d_in[13];
  const float* r_w   = (const float*)d_in[14];
  const float* q_w   = (const float*)d_in[15];
  const float* w_vi  = (const float*)d_in[16];
  const float* fc1_w = (const float*)d_in[17];
  const float* fc1_b = (const float*)d_in[18];
  const float* fc2_w = (const float*)d_in[19];
  const float* fc2_b = (const float*)d_in[20];
  const float* cv_w  = (const float*)d_in[21];
  const float* cv_b  = (const float*)d_in[22];
  // K (d_in[23]) fixed to 36 by setup; loop count is compile-time.

  char* ws = (char*)d_ws;
  unsigned short* t2  = (unsigned short*)ws;                       // 125,829,120 B
  unsigned short* t3  = (unsigned short*)(ws + 125829120ull);      // 109,051,904 B
  unsigned short* W2p = (unsigned short*)(ws + 234881024ull);      //     368,640 B
  unsigned short* W3p = (unsigned short*)(ws + 235249664ull);      //     294,912 B
  float*          ST  = (float*)         (ws + 235544576ull);      //       5,920 B
  float* S1 = ST +    0; float* Q1 = ST +  150; float* A1 = ST +  300; float* B1 = ST +  450;
  float* S2 = ST +  600; float* Q2 = ST +  720; float* A2 = ST +  840; float* B2 = ST +  960;
  float* S3 = ST + 1080; float* Q3 = ST + 1180; float* A3 = ST + 1280; float* B3 = ST + 1380;
  // VI buffers aliased over dead t2 region:
  float*          r   = (float*)ws;                          // 2,097,152 B
  unsigned short* qrh = (unsigned short*)(ws + 2097152ull);  // 10,485,760 B (bf16)
  float*          vA  = (float*)(ws + 12582912ull);          // 2,097,152 B
  float*          vB  = (float*)(ws + 14680064ull);          // 2,097,152 B

  hipMemsetAsync(ST, 0, 1480 * sizeof(float), stream);

  repack_w<120, 150, 160><<<720, 256, 0, stream>>>(h2_w, W2p);
  repack_w<100, 120, 128><<<576, 256, 0, stream>>>(h3_w, W3p);

  conv1_stats<<<dim3(1024, 10), 256, 0, stream>>>(X, h1_w, h1_b, S1, Q1);
  bn_finalize<150><<<1, 256, 0, stream>>>(S1, Q1, g1, b1, A1, B1);

  conv2_mfma<<<2048, 256, 0, stream>>>(X, h1_w, h1_b, A1, B1, W2p, h2_b, t2, S2, Q2);
  bn_finalize<120><<<1, 256, 0, stream>>>(S2, Q2, g2, b2, A2, B2);

  conv3_mfma<<<2048, 256, 0, stream>>>(t2, A2, B2, W3p, h3_b, t3, S3, Q3);
  bn_finalize<100><<<1, 256, 0, stream>>>(S3, Q3, g3, b3, A3, B3);

  bn3_reduce_r<<<2048, 256, 0, stream>>>(t3, A3, B3, r_w, r);

  qr_init<<<2048, 256, 0, stream>>>(r, q_w, qrh, vA);
  for (int i = 0; i < 36; i++) {
    const float* vin = (i & 1) ? vB : vA;
    float* vout      = (i & 1) ? vA : vB;
    vi_step<<<2048, 256, 0, stream>>>(vin, qrh, w_vi, vout);
  }

  float* out = (float*)d_out;
  critic_k<<<128, 256, 0, stream>>>(vA, cv_w, cv_b, out);
  action_k<<<128, 128, 0, stream>>>(obs, fc1_w, fc1_b, fc2_w, fc2_b, out);
}